// Round 1
// baseline (669.270 us; speedup 1.0000x reference)
//
#include <hip/hip_runtime.h>

#define S    4096
#define CH   256
#define NB   8

#define QT   32
#define KT   128
#define CKC  32

#define NEG_INF (-3.402823466e38f)

// ---------------------------------------------------------------------------
// out[:, 0:512] = input  (per-batch contiguous copy, float4 vectorized)
__global__ void copy_fl(const float* __restrict__ x, float* __restrict__ out) {
    int i = blockIdx.x * 256 + threadIdx.x;          // float4 index
    const int per_b = 512 * S / 4;                   // 524288
    int b = i / per_b;
    int r = i - b * per_b;
    const float4* src = (const float4*)x;
    float4* dst = (float4*)out;
    dst[(size_t)b * (768 * S / 4) + r] = src[(size_t)b * per_b + r];
}

// ---------------------------------------------------------------------------
// order-preserving compaction: qlist = {s : flag[s]==1}, klist = {s : flag[s]==0}
__global__ void compact(const int* __restrict__ flag, int* __restrict__ cnts,
                        int* __restrict__ qlist, int* __restrict__ klist) {
    __shared__ int sq[256], sk[256];
    int t = threadIdx.x;
    int base = t * 16;
    int f[16];
    int nq = 0, nk = 0;
    #pragma unroll
    for (int i = 0; i < 16; ++i) {
        f[i] = flag[base + i];
        nq += (f[i] == 1);
        nk += (f[i] == 0);
    }
    sq[t] = nq; sk[t] = nk;
    __syncthreads();
    // Hillis-Steele inclusive scan over 256 entries
    for (int off = 1; off < 256; off <<= 1) {
        int vq = sq[t], vk = sk[t];
        int aq = (t >= off) ? sq[t - off] : 0;
        int ak = (t >= off) ? sk[t - off] : 0;
        __syncthreads();
        sq[t] = vq + aq; sk[t] = vk + ak;
        __syncthreads();
    }
    int pq = sq[t] - nq;   // exclusive prefix
    int pk = sk[t] - nk;
    #pragma unroll
    for (int i = 0; i < 16; ++i) {
        if (f[i] == 1)      qlist[pq++] = base + i;
        else                klist[pk++] = base + i;
    }
    if (t == 255) { cnts[0] = sq[255]; cnts[1] = sk[255]; }
}

// ---------------------------------------------------------------------------
// invn[b][k] = 1 / max(||l[b,k,:]||, 1e-12)
__global__ void invnorm_k(const float* __restrict__ x, float* __restrict__ invn) {
    int k = blockIdx.x * 256 + threadIdx.x;
    int b = blockIdx.y;
    const float* base = x + ((size_t)b * 512 + 256) * S + k;
    float acc = 0.f;
    #pragma unroll 8
    for (int c = 0; c < CH; ++c) {
        float v = base[(size_t)c * S];
        acc += v * v;
    }
    invn[b * S + k] = 1.0f / fmaxf(sqrtf(acc), 1e-12f);
}

// ---------------------------------------------------------------------------
// per (b, q-tile): argmax over active k of dot(f[q], l_norm[k])
__launch_bounds__(256)
__global__ void argmax_gemm(const float* __restrict__ x,
                            const int*  __restrict__ cnts,
                            const int*  __restrict__ qlist,
                            const int*  __restrict__ klist,
                            const float* __restrict__ invn,
                            int* __restrict__ idxb) {
    __shared__ float Fs[CH * QT];      // 32 KB, full C panel for this q-tile
    __shared__ float Ls[CKC * KT];     // 16 KB, one c-chunk of the k-tile
    __shared__ int   qi_s[QT];
    __shared__ int   kidx_s[KT];
    __shared__ float invn_s[KT];

    const int Aq = cnts[0];
    const int Ak = cnts[1];
    const int b  = blockIdx.y;
    const int q0 = blockIdx.x * QT;
    if (q0 >= Aq) return;

    const int tid = threadIdx.x;
    const int tq  = tid >> 5;    // 0..7  -> 4 q rows each
    const int tk  = tid & 31;    // 0..31 -> 4 k cols each

    const float* Fm   = x + (size_t)b * 512 * S;     // former, [c][s]
    const float* Lm   = Fm + (size_t)CH * S;         // latter, [c][s]
    const float* invb = invn + b * S;

    if (tid < QT) {
        int qp = q0 + tid;
        qi_s[tid] = qlist[(qp < Aq) ? qp : (Aq - 1)];
    }
    __syncthreads();

    // stage full F panel: Fs[c][i] = Fm[c][qi[i]]
    #pragma unroll
    for (int p = 0; p < (CH * QT) / 256; ++p) {
        int e = p * 256 + tid;
        int c = e >> 5;            // / QT
        int i = e & (QT - 1);
        Fs[e] = Fm[(size_t)c * S + qi_s[i]];
    }

    float rm[4]; int ri[4];
    #pragma unroll
    for (int i = 0; i < 4; ++i) { rm[i] = NEG_INF; ri[i] = 0; }

    const int nkt = (Ak + KT - 1) / KT;
    for (int kt = 0; kt < nkt; ++kt) {
        int kbase = kt * KT;
        __syncthreads();           // previous epilogue done reading kidx_s
        if (tid < KT) {
            int kp = kbase + tid;
            if (kp < Ak) {
                int kk = klist[kp];
                kidx_s[tid] = kk;
                invn_s[tid] = invb[kk];
            } else {
                kidx_s[tid] = -1;
                invn_s[tid] = 0.f;
            }
        }

        float acc[4][4];
        #pragma unroll
        for (int a = 0; a < 4; ++a)
            #pragma unroll
            for (int c = 0; c < 4; ++c) acc[a][c] = 0.f;

        for (int c0 = 0; c0 < CH; c0 += CKC) {
            __syncthreads();       // kidx_s/invn_s visible; compute done with Ls
            // stage Ls[cc][j] = Lm[c0+cc][klist[j]] * invn[klist[j]]
            #pragma unroll
            for (int p = 0; p < (CKC * KT) / 256; ++p) {
                int e  = p * 256 + tid;
                int cc = e >> 7;          // / KT
                int j  = e & (KT - 1);
                int kk = kidx_s[j];
                float v = 0.f;
                if (kk >= 0) v = Lm[(size_t)(c0 + cc) * S + kk] * invn_s[j];
                Ls[e] = v;
            }
            __syncthreads();
            #pragma unroll
            for (int cc = 0; cc < CKC; ++cc) {
                const float4 af = *(const float4*)&Fs[(c0 + cc) * QT + tq * 4];
                const float4 bf = *(const float4*)&Ls[cc * KT + tk * 4];
                float av[4] = { af.x, af.y, af.z, af.w };
                float bv[4] = { bf.x, bf.y, bf.z, bf.w };
                #pragma unroll
                for (int qq = 0; qq < 4; ++qq)
                    #pragma unroll
                    for (int jj = 0; jj < 4; ++jj)
                        acc[qq][jj] += av[qq] * bv[jj];
            }
        }
        __syncthreads();

        // epilogue: fold this k-tile into running (max, idx)
        #pragma unroll
        for (int jj = 0; jj < 4; ++jj) {
            int j  = tk * 4 + jj;
            int kk = kidx_s[j];
            if (kk >= 0) {
                #pragma unroll
                for (int qq = 0; qq < 4; ++qq) {
                    float sv = acc[qq][jj];
                    if (sv > rm[qq]) { rm[qq] = sv; ri[qq] = kk; }
                    else if (sv == rm[qq] && kk < ri[qq]) { ri[qq] = kk; }
                }
            }
        }
    }

    // reduce across the 32 lanes sharing this q-group (smaller idx wins ties)
    #pragma unroll
    for (int qq = 0; qq < 4; ++qq) {
        float m = rm[qq]; int id = ri[qq];
        for (int off = 16; off; off >>= 1) {
            float om = __shfl_xor(m, off, 32);
            int   oi = __shfl_xor(id, off, 32);
            if (om > m || (om == m && oi < id)) { m = om; id = oi; }
        }
        if (tk == 0) {
            int qp = q0 + tq * 4 + qq;
            if (qp < Aq) idxb[b * S + qi_s[tq * 4 + qq]] = id;
        }
    }
}

// ---------------------------------------------------------------------------
// out[b][512+c][q] = flag[q]==1 ? latter[b][c][idx[b][q]] : 0
__global__ void scatter_k(const float* __restrict__ x, const int* __restrict__ flag,
                          const int* __restrict__ idxb, float* __restrict__ out) {
    int e = blockIdx.x * 256 + threadIdx.x;   // 8 * 256 * 4096 total
    int q = e & (S - 1);
    int c = (e >> 12) & 255;
    int b = e >> 20;
    float v = 0.f;
    if (flag[q] == 1) {
        int id = idxb[b * S + q];
        v = x[((size_t)b * 512 + 256 + c) * S + id];
    }
    out[((size_t)b * 768 + 512 + c) * S + q] = v;
}

// ---------------------------------------------------------------------------
extern "C" void kernel_launch(void* const* d_in, const int* in_sizes, int n_in,
                              void* d_out, int out_size, void* d_ws, size_t ws_size,
                              hipStream_t stream) {
    const float* x    = (const float*)d_in[0];
    const int*   flag = (const int*)d_in[2];
    float*       out  = (float*)d_out;

    char* ws = (char*)d_ws;
    int*   cnts  = (int*)ws;                                  // 2 ints
    int*   qlist = (int*)(ws + 64);                           // 4096 ints
    int*   klist = (int*)(ws + 64 + 16384);                   // 4096 ints
    float* invn  = (float*)(ws + 64 + 32768);                 // 8*4096 floats
    int*   idxb  = (int*)(ws + 64 + 32768 + 131072);          // 8*4096 ints

    hipLaunchKernelGGL(copy_fl,     dim3((NB * 512 * S / 4) / 256), dim3(256), 0, stream, x, out);
    hipLaunchKernelGGL(compact,     dim3(1),                        dim3(256), 0, stream, flag, cnts, qlist, klist);
    hipLaunchKernelGGL(invnorm_k,   dim3(S / 256, NB),              dim3(256), 0, stream, x, invn);
    hipLaunchKernelGGL(argmax_gemm, dim3(S / QT, NB),               dim3(256), 0, stream, x, cnts, qlist, klist, invn, idxb);
    hipLaunchKernelGGL(scatter_k,   dim3((NB * CH * S) / 256),      dim3(256), 0, stream, x, flag, idxb, out);
}